// Round 10
// baseline (190.210 us; speedup 1.0000x reference)
//
#include <hip/hip_runtime.h>
#include <cstddef>

#define E_DIM 512
#define HID   640
#define NH    10
#define DK    64
#define LTOT  2054
#define NCLS  527
#define NB    4
#define KC    (-0.0179889460390157f)   // -ln(10000)/512

// Wave64 sum-reduction via DPP (VALU pipe only, no LDS/DS ops).
__device__ __forceinline__ float wave_reduce_sum_dpp(float x) {
    float t;
    t = __int_as_float(__builtin_amdgcn_update_dpp(0, __float_as_int(x), 0x111, 0xf, 0xf, false)); x += t;
    t = __int_as_float(__builtin_amdgcn_update_dpp(0, __float_as_int(x), 0x112, 0xf, 0xf, false)); x += t;
    t = __int_as_float(__builtin_amdgcn_update_dpp(0, __float_as_int(x), 0x114, 0xf, 0xe, false)); x += t;
    t = __int_as_float(__builtin_amdgcn_update_dpp(0, __float_as_int(x), 0x118, 0xf, 0xc, false)); x += t;
    t = __int_as_float(__builtin_amdgcn_update_dpp(0, __float_as_int(x), 0x142, 0xa, 0xf, false)); x += t;
    t = __int_as_float(__builtin_amdgcn_update_dpp(0, __float_as_int(x), 0x143, 0xc, 0xf, false)); x += t;
    return __int_as_float(__builtin_amdgcn_readlane(__float_as_int(x), 63));
}

// Source row pointer for logical feats row n of batch b.
__device__ __forceinline__ const float* row_src(int b, int n,
        const float* au, const float* vi, const float* at,
        const float* vt, const float* bt) {
    if (n < 1024) return au + ((size_t)b*1024 + n)*E_DIM;
    if (n == 1024) return at;
    if (n < 1029) return bt + (size_t)(n-1025)*E_DIM;
    if (n < 2053) return vi + ((size_t)b*1024 + (n-1029))*E_DIM;
    return vt;
}

// K1: per-(h,bm) k-fragment + u-vector + c. grid (NH, 8), block 256.
__global__ __launch_bounds__(256) void ba_ku_kernel(
        const float* __restrict__ audio, const float* __restrict__ video,
        const float* __restrict__ Wk, const float* __restrict__ bk,
        const float* __restrict__ Wq, const float* __restrict__ bq,
        float* __restrict__ uws, float* __restrict__ cws) {
    int h = blockIdx.x, bm = blockIdx.y;
    int b = bm >> 1, m = bm & 1;
    int mrow = m ? 1029 : 0;
    const float* src = m ? (video + (size_t)b*1024*E_DIM)
                         : (audio + (size_t)b*1024*E_DIM);
    int t = threadIdx.x;
    __shared__ float frow[E_DIM];
    __shared__ __align__(16) float kl[DK];
    __shared__ float red[4][DK];
    for (int i = t; i < E_DIM; i += 256) {
        float div = expf((float)(i & ~1) * KC);
        float arg = (float)mrow * div;
        float pe  = (i & 1) ? cosf(arg) : sinf(arg);
        frow[i] = src[i] + pe;
    }
    __syncthreads();
    int d = t & 63, es = t >> 6;
    const float* wkcol = Wk + (size_t)(h*DK) + d;
    float part = 0.f;
    #pragma unroll 8
    for (int e = es*128; e < es*128 + 128; ++e)
        part = fmaf(frow[e], wkcol[(size_t)e*HID], part);
    red[es][d] = part;
    __syncthreads();
    if (t < DK)
        kl[t] = bk[h*DK + t] + red[0][t] + red[1][t] + red[2][t] + red[3][t];
    __syncthreads();
    #pragma unroll
    for (int s = 0; s < 2; ++s) {
        int e = s*256 + t;
        const float4* wq4 = (const float4*)(Wq + (size_t)e*HID + h*DK);
        const float4* k4  = (const float4*)kl;
        float acc = 0.f;
        #pragma unroll
        for (int d4 = 0; d4 < 16; ++d4) {
            float4 w = wq4[d4]; float4 kk = k4[d4];
            acc = fmaf(w.x,kk.x, fmaf(w.y,kk.y, fmaf(w.z,kk.z, fmaf(w.w,kk.w, acc))));
        }
        uws[((size_t)bm*NH + h)*E_DIM + e] = acc * 0.125f;
    }
    if (t < 64) {
        float prod = (t < DK) ? bq[h*DK + t] * kl[t] : 0.f;
        float tot = wave_reduce_sum_dpp(prod);
        if (t == 0) cws[bm*NH + h] = tot * 0.125f;
    }
}

// K2: fused scores + chunk softmax + weighted feature sum — TWO-PHASE.
// Phase A: all CRW scores to registers (no cross-row dependence -> deep prefetch).
// Phase B: weights known, pure independent fma accumulation.
// grid (nch, 5, NB), block 128 = 2 waves; wave owns p-pair; lanes split E.
template<int CRW>
__global__ __launch_bounds__(128) void ba_fused_kernel(
        const float* __restrict__ audio, const float* __restrict__ video,
        const float* __restrict__ atok, const float* __restrict__ vtok,
        const float* __restrict__ btnk,
        const float* __restrict__ uws, const float* __restrict__ cws,
        float* __restrict__ wpart, float* __restrict__ mcs,
        float* __restrict__ lcs, int nch) {
    int b = blockIdx.z, chunk = blockIdx.x, t = threadIdx.x;
    int w = t >> 6, lane = t & 63;
    int pbase = (blockIdx.y*2 + w)*2;
    int eb = lane*8;
    int r0 = chunk*CRW;

    if (r0 >= LTOT) {     // fully-empty tail chunk: write neutral outputs
        #pragma unroll
        for (int i = 0; i < 2; ++i) {
            float* dst = wpart + ((size_t)(b*20 + pbase + i)*nch + chunk)*E_DIM + eb;
            *(float4*)dst       = make_float4(0.f, 0.f, 0.f, 0.f);
            *(float4*)(dst + 4) = make_float4(0.f, 0.f, 0.f, 0.f);
        }
        if (lane < 2) {
            size_t ix = (size_t)(b*20 + pbase + lane)*nch + chunk;
            mcs[ix] = -1e30f;
            lcs[ix] = 0.f;
        }
        return;
    }

    float4 u0[2], u1[2];
    float cadd[2];
    #pragma unroll
    for (int i = 0; i < 2; ++i) {
        const float4* up = (const float4*)(uws + (size_t)(b*20 + pbase + i)*E_DIM + eb);
        u0[i] = up[0]; u1[i] = up[1];
        cadd[i] = cws[b*20 + pbase + i];
    }
    float sn[4], cn[4], sd[4], cd[4], sn0[4], cn0[4];
    #pragma unroll
    for (int q = 0; q < 4; ++q) {
        float dv = expf((float)(eb + 2*q) * KC);
        sd[q] = sinf(dv); cd[q] = cosf(dv);
        float a = (float)r0 * dv;
        sn[q] = sinf(a); cn[q] = cosf(a);
        sn0[q] = sn[q]; cn0[q] = cn[q];
    }
    int rend = min(r0 + CRW, LTOT);

#define ADV_ROT() { \
    _Pragma("unroll") \
    for (int q = 0; q < 4; ++q) { \
        float s2_ = fmaf(sn[q], cd[q],  cn[q]*sd[q]); \
        float c2_ = fmaf(cn[q], cd[q], -sn[q]*sd[q]); \
        sn[q] = s2_; cn[q] = c2_; } }

#define LOAD_FP(fp, rr) { \
    const float* src_ = row_src(b, rr, audio, video, atok, vtok, btnk); \
    float4 a0_ = *(const float4*)(src_ + eb); \
    float4 a1_ = *(const float4*)(src_ + eb + 4); \
    (fp)[0]=a0_.x+sn[0]; (fp)[1]=a0_.y+cn[0]; (fp)[2]=a0_.z+sn[1]; (fp)[3]=a0_.w+cn[1]; \
    (fp)[4]=a1_.x+sn[2]; (fp)[5]=a1_.y+cn[2]; (fp)[6]=a1_.z+sn[3]; (fp)[7]=a1_.w+cn[3]; }

#define DOT8(res, fp, i) { \
    float a_; \
    a_ = (fp)[0]*u0[i].x; \
    a_ = fmaf((fp)[1], u0[i].y, a_); \
    a_ = fmaf((fp)[2], u0[i].z, a_); \
    a_ = fmaf((fp)[3], u0[i].w, a_); \
    a_ = fmaf((fp)[4], u1[i].x, a_); \
    a_ = fmaf((fp)[5], u1[i].y, a_); \
    a_ = fmaf((fp)[6], u1[i].z, a_); \
    a_ = fmaf((fp)[7], u1[i].w, a_); \
    (res) = a_; }

    // ---- Phase A: scores (register arrays, fully unrolled) ----
    float s0v[CRW], s1v[CRW];
    #pragma unroll
    for (int i = 0; i < CRW; ++i) {
        int r = r0 + i;
        bool v = (r < rend);
        int rr = v ? r : (LTOT - 1);
        float fp[8];
        LOAD_FP(fp, rr);
        ADV_ROT();
        float d0, d1;
        DOT8(d0, fp, 0); DOT8(d1, fp, 1);
        float sc0 = wave_reduce_sum_dpp(d0) + cadd[0];
        float sc1 = wave_reduce_sum_dpp(d1) + cadd[1];
        s0v[i] = v ? sc0 : -1e30f;
        s1v[i] = v ? sc1 : -1e30f;
    }
    // ---- M, weights, L ----
    float M0 = -1e30f, M1 = -1e30f;
    #pragma unroll
    for (int i = 0; i < CRW; ++i) {
        M0 = fmaxf(M0, s0v[i]);
        M1 = fmaxf(M1, s1v[i]);
    }
    float L0 = 0.f, L1 = 0.f;
    #pragma unroll
    for (int i = 0; i < CRW; ++i) {
        s0v[i] = __expf(s0v[i] - M0); L0 += s0v[i];   // s*v now holds weights
        s1v[i] = __expf(s1v[i] - M1); L1 += s1v[i];
    }
    // ---- Phase B: pure fma accumulation (rows L2-hot) ----
    #pragma unroll
    for (int q = 0; q < 4; ++q) { sn[q] = sn0[q]; cn[q] = cn0[q]; }
    float acc[2][8];
    #pragma unroll
    for (int i = 0; i < 2; ++i)
        #pragma unroll
        for (int j = 0; j < 8; ++j) acc[i][j] = 0.f;
    #pragma unroll
    for (int i = 0; i < CRW; ++i) {
        int r = r0 + i;
        int rr = (r < rend) ? r : (LTOT - 1);    // weights are 0 for invalid rows
        float fp[8];
        LOAD_FP(fp, rr);
        ADV_ROT();
        float w0 = s0v[i], w1 = s1v[i];
        #pragma unroll
        for (int j = 0; j < 8; ++j) {
            acc[0][j] = fmaf(w0, fp[j], acc[0][j]);
            acc[1][j] = fmaf(w1, fp[j], acc[1][j]);
        }
    }
    #pragma unroll
    for (int i = 0; i < 2; ++i) {
        float* dst = wpart + ((size_t)(b*20 + pbase + i)*nch + chunk)*E_DIM + eb;
        *(float4*)dst       = make_float4(acc[i][0], acc[i][1], acc[i][2], acc[i][3]);
        *(float4*)(dst + 4) = make_float4(acc[i][4], acc[i][5], acc[i][6], acc[i][7]);
    }
    float mv = (lane == 0) ? M0 : M1;
    float lv = (lane == 0) ? L0 : L1;
    if (lane < 2) {
        size_t ix = (size_t)(b*20 + pbase + lane)*nch + chunk;
        mcs[ix] = mv;
        lcs[ix] = lv;
    }
#undef ADV_ROT
#undef LOAD_FP
#undef DOT8
}

// K3: reduce chunk partials with softmax rescale, project through Wv.
// grid (NH, 8), block 1024 = 16 waves. Parallel M/L reduction, streaming wpart.
__global__ __launch_bounds__(1024) void ba_outraw_kernel(
        const float* __restrict__ wpart, const float* __restrict__ mcs,
        const float* __restrict__ lcs,
        const float* __restrict__ Wv, const float* __restrict__ bv,
        float* __restrict__ orow, int nch) {
    int h = blockIdx.x, bm = blockIdx.y, t = threadIdx.x;
    int b = bm >> 1, m = bm & 1, p = m*10 + h;
    __shared__ float ml[128], ll[128], coefs[128];
    __shared__ float Msh, invLsh;
    __shared__ float wh[E_DIM];
    __shared__ float sh[2][E_DIM];
    __shared__ float red[16][64];
    const float* mrow = mcs + (size_t)(b*20 + p)*nch;
    const float* lrow = lcs + (size_t)(b*20 + p)*nch;
    if (t < nch) { ml[t] = mrow[t]; ll[t] = lrow[t]; }
    __syncthreads();
    if (t < 64) {
        float mv = -1e30f;
        for (int c = t; c < nch; c += 64) mv = fmaxf(mv, ml[c]);
        #pragma unroll
        for (int off = 1; off < 64; off <<= 1) mv = fmaxf(mv, __shfl_xor(mv, off, 64));
        if (t == 0) Msh = mv;
    }
    __syncthreads();
    float M = Msh;
    if (t < 64) {
        float lv = 0.f;
        for (int c = t; c < nch; c += 64) lv += ll[c] * __expf(ml[c] - M);
        lv = wave_reduce_sum_dpp(lv);
        if (t == 0) invLsh = 1.0f / lv;
    }
    __syncthreads();
    if (t < nch) coefs[t] = __expf(ml[t] - M) * invLsh;
    __syncthreads();
    int e = t & 511, half = t >> 9;
    const float* basep = wpart + (size_t)(b*20 + p)*nch*E_DIM;
    float acc = 0.f;
    int c0 = half*(nch >> 1), c1 = c0 + (nch >> 1);
    for (int c = c0; c < c1; ++c)
        acc = fmaf(basep[(size_t)c*E_DIM + e], coefs[c], acc);
    sh[half][e] = acc;
    __syncthreads();
    if (t < E_DIM) wh[t] = sh[0][t] + sh[1][t];
    __syncthreads();
    int d = t & 63, es = t >> 6;          // es 0..15, 32 e's each
    float part = 0.f;
    #pragma unroll 8
    for (int e2 = es*32; e2 < es*32 + 32; ++e2)
        part = fmaf(wh[e2], Wv[(size_t)e2*HID + h*DK + d], part);
    red[es][d] = part;
    __syncthreads();
    if (t < 64) {
        float s = 0.f;
        #pragma unroll
        for (int i = 0; i < 16; ++i) s += red[i][t];
        orow[(size_t)bm*HID + h*DK + t] = bv[h*DK + t] + s;
    }
}

// K4: fused layernorm + class predictions, parallel over c-tiles and j-groups.
// grid (9, NB), block 512 = 64 c-lanes x 8 j-groups. No atomics.
__global__ __launch_bounds__(512) void ba_lnpred_kernel(
        const float* __restrict__ orow,
        const float* __restrict__ g, const float* __restrict__ bb,
        const float* __restrict__ Wap, const float* __restrict__ bap,
        const float* __restrict__ Wvp, const float* __restrict__ bvp,
        float* __restrict__ out) {
    int b = blockIdx.y, t = threadIdx.x;
    const float* A = orow + (size_t)(2*b)*HID;
    const float* V = orow + (size_t)(2*b + 1)*HID;
    __shared__ float lnA[HID], lnV[HID];
    __shared__ float wred[4][8];
    __shared__ float psum[8][2][64];
    float sA = 0.f, qA = 0.f, sV = 0.f, qV = 0.f;
    for (int i = t; i < HID; i += 512) {
        float xa = A[i]; sA += xa; qA = fmaf(xa, xa, qA);
        float xv = V[i]; sV += xv; qV = fmaf(xv, xv, qV);
    }
    sA = wave_reduce_sum_dpp(sA); qA = wave_reduce_sum_dpp(qA);
    sV = wave_reduce_sum_dpp(sV); qV = wave_reduce_sum_dpp(qV);
    int w = t >> 6, lane = t & 63;
    if (lane == 0) { wred[0][w] = sA; wred[1][w] = qA; wred[2][w] = sV; wred[3][w] = qV; }
    __syncthreads();
    float tsA = 0.f, tqA = 0.f, tsV = 0.f, tqV = 0.f;
    #pragma unroll
    for (int i = 0; i < 8; ++i) {
        tsA += wred[0][i]; tqA += wred[1][i]; tsV += wred[2][i]; tqV += wred[3][i];
    }
    float meanA = tsA*(1.0f/HID), varA = tqA*(1.0f/HID) - meanA*meanA;
    float meanV = tsV*(1.0f/HID), varV = tqV*(1.0f/HID) - meanV*meanV;
    float rA = rsqrtf(varA + 1e-5f), rV = rsqrtf(varV + 1e-5f);
    for (int i = t; i < HID; i += 512) {
        float gg = g[i], bbv = bb[i];
        lnA[i] = (A[i] - meanA)*rA*gg + bbv;
        lnV[i] = (V[i] - meanV)*rV*gg + bbv;
    }
    __syncthreads();
    int c = blockIdx.x*64 + lane;
    int cc = (c < NCLS) ? c : (NCLS - 1);      // clamp to stay in-bounds
    int j0 = w*80;
    float sa = 0.f, sv = 0.f;
    #pragma unroll 8
    for (int j = j0; j < j0 + 80; ++j) {
        sa = fmaf(lnA[j], Wap[(size_t)j*NCLS + cc], sa);
        sv = fmaf(lnV[j], Wvp[(size_t)j*NCLS + cc], sv);
    }
    psum[w][0][lane] = sa;
    psum[w][1][lane] = sv;
    __syncthreads();
    if (t < 64 && c < NCLS) {
        float ta = 0.f, tv = 0.f;
        #pragma unroll
        for (int i = 0; i < 8; ++i) { ta += psum[i][0][t]; tv += psum[i][1][t]; }
        out[(size_t)b*NCLS + c] = 0.5f*(ta + tv + bap[c] + bvp[c]);
    }
}

extern "C" void kernel_launch(void* const* d_in, const int* in_sizes, int n_in,
                              void* d_out, int out_size, void* d_ws, size_t ws_size,
                              hipStream_t stream) {
    const float* audio = (const float*)d_in[0];
    const float* video = (const float*)d_in[1];
    const float* atok  = (const float*)d_in[2];
    const float* vtok  = (const float*)d_in[3];
    const float* btnk  = (const float*)d_in[4];
    const float* Wk    = (const float*)d_in[5];
    const float* bk    = (const float*)d_in[6];
    const float* Wq    = (const float*)d_in[7];
    const float* bq    = (const float*)d_in[8];
    const float* Wv    = (const float*)d_in[9];
    const float* bv    = (const float*)d_in[10];
    const float* ln_g  = (const float*)d_in[11];
    const float* ln_b  = (const float*)d_in[12];
    const float* Wap   = (const float*)d_in[13];
    const float* bap   = (const float*)d_in[14];
    const float* Wvp   = (const float*)d_in[15];
    const float* bvp   = (const float*)d_in[16];
    float* out = (float*)d_out;
    float* ws  = (float*)d_ws;

    auto need = [](int nch) -> size_t {
        return (size_t)(8*NH*E_DIM) + 80
             + (size_t)NB*nch*20*E_DIM + 2*(size_t)NB*nch*20
             + 8*HID;
    };
    int nch = 40;
    if (ws_size >= need(128)*sizeof(float)) nch = 128;
    else if (ws_size >= need(64)*sizeof(float)) nch = 64;

    float* uws   = ws;
    float* cws   = uws + 8*NH*E_DIM;
    float* wpart = cws + 80;
    float* mcs   = wpart + (size_t)NB*nch*20*E_DIM;
    float* lcs   = mcs + (size_t)NB*nch*20;
    float* orw   = lcs + (size_t)NB*nch*20;

    ba_ku_kernel<<<dim3(NH, 8), 256, 0, stream>>>(audio, video, Wk, bk, Wq, bq, uws, cws);
    if (nch == 128)
        ba_fused_kernel<17><<<dim3(128, 5, NB), 128, 0, stream>>>(
            audio, video, atok, vtok, btnk, uws, cws, wpart, mcs, lcs, 128);
    else if (nch == 64)
        ba_fused_kernel<33><<<dim3(64, 5, NB), 128, 0, stream>>>(
            audio, video, atok, vtok, btnk, uws, cws, wpart, mcs, lcs, 64);
    else
        ba_fused_kernel<52><<<dim3(40, 5, NB), 128, 0, stream>>>(
            audio, video, atok, vtok, btnk, uws, cws, wpart, mcs, lcs, 40);
    ba_outraw_kernel<<<dim3(NH, 8), 1024, 0, stream>>>(wpart, mcs, lcs, Wv, bv, orw, nch);
    ba_lnpred_kernel<<<dim3(9, NB), 512, 0, stream>>>(orw, ln_g, ln_b,
                                                      Wap, bap, Wvp, bvp, out);
}

// Round 11
// 162.171 us; speedup vs baseline: 1.1729x; 1.1729x over previous
//
#include <hip/hip_runtime.h>
#include <cstddef>

#define E_DIM 512
#define HID   640
#define NH    10
#define DK    64
#define LTOT  2054
#define NCLS  527
#define NB    4
#define KC    (-0.0179889460390157f)   // -ln(10000)/512

// Wave64 sum-reduction via DPP (VALU pipe only, no LDS/DS ops).
__device__ __forceinline__ float wave_reduce_sum_dpp(float x) {
    float t;
    t = __int_as_float(__builtin_amdgcn_update_dpp(0, __float_as_int(x), 0x111, 0xf, 0xf, false)); x += t;
    t = __int_as_float(__builtin_amdgcn_update_dpp(0, __float_as_int(x), 0x112, 0xf, 0xf, false)); x += t;
    t = __int_as_float(__builtin_amdgcn_update_dpp(0, __float_as_int(x), 0x114, 0xf, 0xe, false)); x += t;
    t = __int_as_float(__builtin_amdgcn_update_dpp(0, __float_as_int(x), 0x118, 0xf, 0xc, false)); x += t;
    t = __int_as_float(__builtin_amdgcn_update_dpp(0, __float_as_int(x), 0x142, 0xa, 0xf, false)); x += t;
    t = __int_as_float(__builtin_amdgcn_update_dpp(0, __float_as_int(x), 0x143, 0xc, 0xf, false)); x += t;
    return __int_as_float(__builtin_amdgcn_readlane(__float_as_int(x), 63));
}

// Source row pointer for logical feats row n of batch b.
__device__ __forceinline__ const float* row_src(int b, int n,
        const float* au, const float* vi, const float* at,
        const float* vt, const float* bt) {
    if (n < 1024) return au + ((size_t)b*1024 + n)*E_DIM;
    if (n == 1024) return at;
    if (n < 1029) return bt + (size_t)(n-1025)*E_DIM;
    if (n < 2053) return vi + ((size_t)b*1024 + (n-1029))*E_DIM;
    return vt;
}

// K1: per-(h,bm) k-fragment + u-vector + c. grid (NH, 8), block 256.
__global__ __launch_bounds__(256) void ba_ku_kernel(
        const float* __restrict__ audio, const float* __restrict__ video,
        const float* __restrict__ Wk, const float* __restrict__ bk,
        const float* __restrict__ Wq, const float* __restrict__ bq,
        float* __restrict__ uws, float* __restrict__ cws) {
    int h = blockIdx.x, bm = blockIdx.y;
    int b = bm >> 1, m = bm & 1;
    int mrow = m ? 1029 : 0;
    const float* src = m ? (video + (size_t)b*1024*E_DIM)
                         : (audio + (size_t)b*1024*E_DIM);
    int t = threadIdx.x;
    __shared__ float frow[E_DIM];
    __shared__ __align__(16) float kl[DK];
    __shared__ float red[4][DK];
    for (int i = t; i < E_DIM; i += 256) {
        float div = expf((float)(i & ~1) * KC);
        float arg = (float)mrow * div;
        float pe  = (i & 1) ? cosf(arg) : sinf(arg);
        frow[i] = src[i] + pe;
    }
    __syncthreads();
    int d = t & 63, es = t >> 6;
    const float* wkcol = Wk + (size_t)(h*DK) + d;
    float part = 0.f;
    #pragma unroll 8
    for (int e = es*128; e < es*128 + 128; ++e)
        part = fmaf(frow[e], wkcol[(size_t)e*HID], part);
    red[es][d] = part;
    __syncthreads();
    if (t < DK)
        kl[t] = bk[h*DK + t] + red[0][t] + red[1][t] + red[2][t] + red[3][t];
    __syncthreads();
    #pragma unroll
    for (int s = 0; s < 2; ++s) {
        int e = s*256 + t;
        const float4* wq4 = (const float4*)(Wq + (size_t)e*HID + h*DK);
        const float4* k4  = (const float4*)kl;
        float acc = 0.f;
        #pragma unroll
        for (int d4 = 0; d4 < 16; ++d4) {
            float4 w = wq4[d4]; float4 kk = k4[d4];
            acc = fmaf(w.x,kk.x, fmaf(w.y,kk.y, fmaf(w.z,kk.z, fmaf(w.w,kk.w, acc))));
        }
        uws[((size_t)bm*NH + h)*E_DIM + e] = acc * 0.125f;
    }
    if (t < 64) {
        float prod = (t < DK) ? bq[h*DK + t] * kl[t] : 0.f;
        float tot = wave_reduce_sum_dpp(prod);
        if (t == 0) cws[bm*NH + h] = tot * 0.125f;
    }
}

// K2: fused scores + online softmax + weighted feature sum.
// grid (nch, 5, NB), block 128 = 2 waves, wave owns one p-pair; lanes split E.
// Rows processed in groups of 4: 8 independent reduce chains interleave,
// loads issue 4 rows deep; online state updated after the group.
__global__ __launch_bounds__(128) void ba_fused_kernel(
        const float* __restrict__ audio, const float* __restrict__ video,
        const float* __restrict__ atok, const float* __restrict__ vtok,
        const float* __restrict__ btnk,
        const float* __restrict__ uws, const float* __restrict__ cws,
        float* __restrict__ wpart, float* __restrict__ mcs,
        float* __restrict__ lcs, int nch, int crw) {
    int b = blockIdx.z, chunk = blockIdx.x, t = threadIdx.x;
    int w = t >> 6, lane = t & 63;
    int pbase = (blockIdx.y*2 + w)*2;
    int eb = lane*8;
    float4 u0[2], u1[2];
    float cadd[2];
    #pragma unroll
    for (int i = 0; i < 2; ++i) {
        const float4* up = (const float4*)(uws + (size_t)(b*20 + pbase + i)*E_DIM + eb);
        u0[i] = up[0]; u1[i] = up[1];
        cadd[i] = cws[b*20 + pbase + i];
    }
    int r0 = chunk*crw;
    float sn[4], cn[4], sd[4], cd[4];
    #pragma unroll
    for (int q = 0; q < 4; ++q) {
        float dv = expf((float)(eb + 2*q) * KC);
        sd[q] = sinf(dv); cd[q] = cosf(dv);
        float a = (float)r0 * dv;
        sn[q] = sinf(a); cn[q] = cosf(a);
    }
    float m[2], l[2], acc[2][8];
    #pragma unroll
    for (int i = 0; i < 2; ++i) {
        m[i] = -1e30f; l[i] = 0.f;
        #pragma unroll
        for (int j = 0; j < 8; ++j) acc[i][j] = 0.f;
    }
    int rend = min(r0 + crw, LTOT);

#define ADV_ROT() { \
    _Pragma("unroll") \
    for (int q = 0; q < 4; ++q) { \
        float s2_ = fmaf(sn[q], cd[q],  cn[q]*sd[q]); \
        float c2_ = fmaf(cn[q], cd[q], -sn[q]*sd[q]); \
        sn[q] = s2_; cn[q] = c2_; } }

#define MAKE_FP(fp, x0, x1) { \
    (fp)[0]=(x0).x+sn[0]; (fp)[1]=(x0).y+cn[0]; (fp)[2]=(x0).z+sn[1]; (fp)[3]=(x0).w+cn[1]; \
    (fp)[4]=(x1).x+sn[2]; (fp)[5]=(x1).y+cn[2]; (fp)[6]=(x1).z+sn[3]; (fp)[7]=(x1).w+cn[3]; }

#define DOT8(res, fp, i) { \
    float a_; \
    a_ = (fp)[0]*u0[i].x; \
    a_ = fmaf((fp)[1], u0[i].y, a_); \
    a_ = fmaf((fp)[2], u0[i].z, a_); \
    a_ = fmaf((fp)[3], u0[i].w, a_); \
    a_ = fmaf((fp)[4], u1[i].x, a_); \
    a_ = fmaf((fp)[5], u1[i].y, a_); \
    a_ = fmaf((fp)[6], u1[i].z, a_); \
    a_ = fmaf((fp)[7], u1[i].w, a_); \
    (res) = a_; }

#define SOFT_UPD(i, sc, fp) { \
    if ((sc) > m[i]) { \
        float scale_ = __expf(m[i] - (sc)); \
        m[i] = (sc); \
        l[i] = fmaf(l[i], scale_, 1.f); \
        _Pragma("unroll") \
        for (int j = 0; j < 8; ++j) acc[i][j] = fmaf(acc[i][j], scale_, (fp)[j]); \
    } else { \
        float wg_ = __expf((sc) - m[i]); \
        l[i] += wg_; \
        _Pragma("unroll") \
        for (int j = 0; j < 8; ++j) acc[i][j] = fmaf(wg_, (fp)[j], acc[i][j]); } }

    int r = r0;
    for (; r + 3 < rend; r += 4) {
        const float* s0p = row_src(b, r,   audio, video, atok, vtok, btnk);
        const float* s1p = row_src(b, r+1, audio, video, atok, vtok, btnk);
        const float* s2p = row_src(b, r+2, audio, video, atok, vtok, btnk);
        const float* s3p = row_src(b, r+3, audio, video, atok, vtok, btnk);
        float4 x00 = *(const float4*)(s0p + eb), x01 = *(const float4*)(s0p + eb + 4);
        float4 x10 = *(const float4*)(s1p + eb), x11 = *(const float4*)(s1p + eb + 4);
        float4 x20 = *(const float4*)(s2p + eb), x21 = *(const float4*)(s2p + eb + 4);
        float4 x30 = *(const float4*)(s3p + eb), x31 = *(const float4*)(s3p + eb + 4);
        float fp0[8], fp1[8], fp2[8], fp3[8];
        MAKE_FP(fp0, x00, x01); ADV_ROT();
        MAKE_FP(fp1, x10, x11); ADV_ROT();
        MAKE_FP(fp2, x20, x21); ADV_ROT();
        MAKE_FP(fp3, x30, x31); ADV_ROT();
        float d0, d1, d2, d3, d4, d5, d6, d7;
        DOT8(d0, fp0, 0); DOT8(d1, fp0, 1);
        DOT8(d2, fp1, 0); DOT8(d3, fp1, 1);
        DOT8(d4, fp2, 0); DOT8(d5, fp2, 1);
        DOT8(d6, fp3, 0); DOT8(d7, fp3, 1);
        // 8 independent DPP chains — interleaved by the scheduler
        float sc0 = wave_reduce_sum_dpp(d0) + cadd[0];
        float sc1 = wave_reduce_sum_dpp(d1) + cadd[1];
        float sc2 = wave_reduce_sum_dpp(d2) + cadd[0];
        float sc3 = wave_reduce_sum_dpp(d3) + cadd[1];
        float sc4 = wave_reduce_sum_dpp(d4) + cadd[0];
        float sc5 = wave_reduce_sum_dpp(d5) + cadd[1];
        float sc6 = wave_reduce_sum_dpp(d6) + cadd[0];
        float sc7 = wave_reduce_sum_dpp(d7) + cadd[1];
        SOFT_UPD(0, sc0, fp0); SOFT_UPD(0, sc2, fp1);
        SOFT_UPD(0, sc4, fp2); SOFT_UPD(0, sc6, fp3);
        SOFT_UPD(1, sc1, fp0); SOFT_UPD(1, sc3, fp1);
        SOFT_UPD(1, sc5, fp2); SOFT_UPD(1, sc7, fp3);
    }
    for (; r < rend; ++r) {
        const float* s0p = row_src(b, r, audio, video, atok, vtok, btnk);
        float4 x00 = *(const float4*)(s0p + eb), x01 = *(const float4*)(s0p + eb + 4);
        float fp0[8];
        MAKE_FP(fp0, x00, x01); ADV_ROT();
        float d0, d1;
        DOT8(d0, fp0, 0); DOT8(d1, fp0, 1);
        float sc0 = wave_reduce_sum_dpp(d0) + cadd[0];
        float sc1 = wave_reduce_sum_dpp(d1) + cadd[1];
        SOFT_UPD(0, sc0, fp0);
        SOFT_UPD(1, sc1, fp0);
    }
    #pragma unroll
    for (int i = 0; i < 2; ++i) {
        float* dst = wpart + ((size_t)(b*20 + pbase + i)*nch + chunk)*E_DIM + eb;
        *(float4*)dst       = make_float4(acc[i][0], acc[i][1], acc[i][2], acc[i][3]);
        *(float4*)(dst + 4) = make_float4(acc[i][4], acc[i][5], acc[i][6], acc[i][7]);
    }
    float mv = (lane == 0) ? m[0] : m[1];
    float lv = (lane == 0) ? l[0] : l[1];
    if (lane < 2) {
        size_t ix = (size_t)(b*20 + pbase + lane)*nch + chunk;
        mcs[ix] = mv;
        lcs[ix] = lv;
    }
#undef ADV_ROT
#undef MAKE_FP
#undef DOT8
#undef SOFT_UPD
}

// K3: reduce chunk partials with softmax rescale, project through Wv.
// grid (NH, 8), block 1024 = 16 waves. Parallel M/L reduction, streaming wpart.
__global__ __launch_bounds__(1024) void ba_outraw_kernel(
        const float* __restrict__ wpart, const float* __restrict__ mcs,
        const float* __restrict__ lcs,
        const float* __restrict__ Wv, const float* __restrict__ bv,
        float* __restrict__ orow, int nch) {
    int h = blockIdx.x, bm = blockIdx.y, t = threadIdx.x;
    int b = bm >> 1, m = bm & 1, p = m*10 + h;
    __shared__ float ml[128], ll[128], coefs[128];
    __shared__ float Msh, invLsh;
    __shared__ float wh[E_DIM];
    __shared__ float sh[2][E_DIM];
    __shared__ float red[16][64];
    const float* mrow = mcs + (size_t)(b*20 + p)*nch;
    const float* lrow = lcs + (size_t)(b*20 + p)*nch;
    if (t < nch) { ml[t] = mrow[t]; ll[t] = lrow[t]; }
    __syncthreads();
    if (t < 64) {
        float mv = -1e30f;
        for (int c = t; c < nch; c += 64) mv = fmaxf(mv, ml[c]);
        #pragma unroll
        for (int off = 1; off < 64; off <<= 1) mv = fmaxf(mv, __shfl_xor(mv, off, 64));
        if (t == 0) Msh = mv;
    }
    __syncthreads();
    float M = Msh;
    if (t < 64) {
        float lv = 0.f;
        for (int c = t; c < nch; c += 64) lv += ll[c] * __expf(ml[c] - M);
        lv = wave_reduce_sum_dpp(lv);
        if (t == 0) invLsh = 1.0f / lv;
    }
    __syncthreads();
    if (t < nch) coefs[t] = __expf(ml[t] - M) * invLsh;
    __syncthreads();
    int e = t & 511, half = t >> 9;
    const float* basep = wpart + (size_t)(b*20 + p)*nch*E_DIM;
    float acc = 0.f;
    int c0 = half*(nch >> 1), c1 = c0 + (nch >> 1);
    for (int c = c0; c < c1; ++c)
        acc = fmaf(basep[(size_t)c*E_DIM + e], coefs[c], acc);
    sh[half][e] = acc;
    __syncthreads();
    if (t < E_DIM) wh[t] = sh[0][t] + sh[1][t];
    __syncthreads();
    int d = t & 63, es = t >> 6;          // es 0..15, 32 e's each
    float part = 0.f;
    #pragma unroll 8
    for (int e2 = es*32; e2 < es*32 + 32; ++e2)
        part = fmaf(wh[e2], Wv[(size_t)e2*HID + h*DK + d], part);
    red[es][d] = part;
    __syncthreads();
    if (t < 64) {
        float s = 0.f;
        #pragma unroll
        for (int i = 0; i < 16; ++i) s += red[i][t];
        orow[(size_t)bm*HID + h*DK + t] = bv[h*DK + t] + s;
    }
}

// K4: fused layernorm + class predictions, parallel over c-tiles and j-groups.
// grid (9, NB), block 512 = 64 c-lanes x 8 j-groups. No atomics.
__global__ __launch_bounds__(512) void ba_lnpred_kernel(
        const float* __restrict__ orow,
        const float* __restrict__ g, const float* __restrict__ bb,
        const float* __restrict__ Wap, const float* __restrict__ bap,
        const float* __restrict__ Wvp, const float* __restrict__ bvp,
        float* __restrict__ out) {
    int b = blockIdx.y, t = threadIdx.x;
    const float* A = orow + (size_t)(2*b)*HID;
    const float* V = orow + (size_t)(2*b + 1)*HID;
    __shared__ float lnA[HID], lnV[HID];
    __shared__ float wred[4][8];
    __shared__ float psum[8][2][64];
    float sA = 0.f, qA = 0.f, sV = 0.f, qV = 0.f;
    for (int i = t; i < HID; i += 512) {
        float xa = A[i]; sA += xa; qA = fmaf(xa, xa, qA);
        float xv = V[i]; sV += xv; qV = fmaf(xv, xv, qV);
    }
    sA = wave_reduce_sum_dpp(sA); qA = wave_reduce_sum_dpp(qA);
    sV = wave_reduce_sum_dpp(sV); qV = wave_reduce_sum_dpp(qV);
    int w = t >> 6, lane = t & 63;
    if (lane == 0) { wred[0][w] = sA; wred[1][w] = qA; wred[2][w] = sV; wred[3][w] = qV; }
    __syncthreads();
    float tsA = 0.f, tqA = 0.f, tsV = 0.f, tqV = 0.f;
    #pragma unroll
    for (int i = 0; i < 8; ++i) {
        tsA += wred[0][i]; tqA += wred[1][i]; tsV += wred[2][i]; tqV += wred[3][i];
    }
    float meanA = tsA*(1.0f/HID), varA = tqA*(1.0f/HID) - meanA*meanA;
    float meanV = tsV*(1.0f/HID), varV = tqV*(1.0f/HID) - meanV*meanV;
    float rA = rsqrtf(varA + 1e-5f), rV = rsqrtf(varV + 1e-5f);
    for (int i = t; i < HID; i += 512) {
        float gg = g[i], bbv = bb[i];
        lnA[i] = (A[i] - meanA)*rA*gg + bbv;
        lnV[i] = (V[i] - meanV)*rV*gg + bbv;
    }
    __syncthreads();
    int c = blockIdx.x*64 + lane;
    int cc = (c < NCLS) ? c : (NCLS - 1);      // clamp to stay in-bounds
    int j0 = w*80;
    float sa = 0.f, sv = 0.f;
    #pragma unroll 8
    for (int j = j0; j < j0 + 80; ++j) {
        sa = fmaf(lnA[j], Wap[(size_t)j*NCLS + cc], sa);
        sv = fmaf(lnV[j], Wvp[(size_t)j*NCLS + cc], sv);
    }
    psum[w][0][lane] = sa;
    psum[w][1][lane] = sv;
    __syncthreads();
    if (t < 64 && c < NCLS) {
        float ta = 0.f, tv = 0.f;
        #pragma unroll
        for (int i = 0; i < 8; ++i) { ta += psum[i][0][t]; tv += psum[i][1][t]; }
        out[(size_t)b*NCLS + c] = 0.5f*(ta + tv + bap[c] + bvp[c]);
    }
}

extern "C" void kernel_launch(void* const* d_in, const int* in_sizes, int n_in,
                              void* d_out, int out_size, void* d_ws, size_t ws_size,
                              hipStream_t stream) {
    const float* audio = (const float*)d_in[0];
    const float* video = (const float*)d_in[1];
    const float* atok  = (const float*)d_in[2];
    const float* vtok  = (const float*)d_in[3];
    const float* btnk  = (const float*)d_in[4];
    const float* Wk    = (const float*)d_in[5];
    const float* bk    = (const float*)d_in[6];
    const float* Wq    = (const float*)d_in[7];
    const float* bq    = (const float*)d_in[8];
    const float* Wv    = (const float*)d_in[9];
    const float* bv    = (const float*)d_in[10];
    const float* ln_g  = (const float*)d_in[11];
    const float* ln_b  = (const float*)d_in[12];
    const float* Wap   = (const float*)d_in[13];
    const float* bap   = (const float*)d_in[14];
    const float* Wvp   = (const float*)d_in[15];
    const float* bvp   = (const float*)d_in[16];
    float* out = (float*)d_out;
    float* ws  = (float*)d_ws;

    auto need = [](int nch) -> size_t {
        return (size_t)(8*NH*E_DIM) + 80
             + (size_t)NB*nch*20*E_DIM + 2*(size_t)NB*nch*20
             + 8*HID;
    };
    int nch = 40;
    if (ws_size >= need(128)*sizeof(float)) nch = 128;
    else if (ws_size >= need(64)*sizeof(float)) nch = 64;
    int crw = (LTOT + nch - 1) / nch;

    float* uws   = ws;
    float* cws   = uws + 8*NH*E_DIM;
    float* wpart = cws + 80;
    float* mcs   = wpart + (size_t)NB*nch*20*E_DIM;
    float* lcs   = mcs + (size_t)NB*nch*20;
    float* orw   = lcs + (size_t)NB*nch*20;

    ba_ku_kernel<<<dim3(NH, 8), 256, 0, stream>>>(audio, video, Wk, bk, Wq, bq, uws, cws);
    ba_fused_kernel<<<dim3(nch, 5, NB), 128, 0, stream>>>(audio, video, atok, vtok, btnk,
                                                          uws, cws, wpart, mcs, lcs, nch, crw);
    ba_outraw_kernel<<<dim3(NH, 8), 1024, 0, stream>>>(wpart, mcs, lcs, Wv, bv, orw, nch);
    ba_lnpred_kernel<<<dim3(9, NB), 512, 0, stream>>>(orw, ln_g, ln_b,
                                                      Wap, bap, Wvp, bvp, out);
}